// Round 1
// baseline (182.740 us; speedup 1.0000x reference)
//
#include <hip/hip_runtime.h>

#define BATCH 64
#define NN 256
#define MM 256
#define DD 128
#define BIG 1e30f

// softmin2(a,b) = -log(exp(-a)+exp(-b)) = mn - log(1 + exp(mn-mx))
// logsumexp is associative, so softmin3(a,b,c) == softmin2(softmin2(a,c), b) exactly.
__device__ __forceinline__ float softmin2(float a, float b) {
    float mn = fminf(a, b);
    float mx = fmaxf(a, b);
    float e  = __expf(mn - mx);          // in [0,1]
    return mn - __logf(1.0f + e);
}

// ---------------- kernel 1: row squared-norms ----------------
// rows 0..16383 = x rows (b*256+i), rows 16384..32767 = y rows (b*256+j)
__global__ __launch_bounds__(256) void norms_kernel(const float* __restrict__ x,
                                                    const float* __restrict__ y,
                                                    float* __restrict__ norm_buf) {
    int wid  = threadIdx.x >> 6;
    int lane = threadIdx.x & 63;
    int row  = blockIdx.x * 4 + wid;     // 0..32767, grid=8192
    const float* src = (row < BATCH * NN)
                     ? (x + (size_t)row * DD)
                     : (y + (size_t)(row - BATCH * NN) * DD);
    float2 v = reinterpret_cast<const float2*>(src)[lane];  // 128 floats = 64 lanes x 2
    float s = v.x * v.x + v.y * v.y;
    #pragma unroll
    for (int o = 32; o; o >>= 1) s += __shfl_xor(s, o);
    if (lane == 0) norm_buf[row] = s;
}

// ---------------- kernel 2: batched dot products ----------------
// grid (BATCH, 8): block computes dot[b][i0..i0+31][0..255].
// LDS: y-chunk [256 rows][32 d] with XOR-swizzled float4 slots, x-chunk [32][32].
__global__ __launch_bounds__(256) void cost_kernel(const float* __restrict__ x,
                                                   const float* __restrict__ y,
                                                   float* __restrict__ dotm) {
    __shared__ float ysh[MM * 32];   // 32 KB
    __shared__ float xsh[32 * 32];   // 4 KB
    int b  = blockIdx.x;
    int i0 = blockIdx.y * 32;
    int t  = threadIdx.x;
    int ti = t >> 5;                 // 0..7  -> rows i0+ti*4+{0..3}
    int tj = t & 31;                 // 0..31 -> cols tj+32*{0..7}
    const float* xb = x + ((size_t)b * NN + i0) * DD;
    const float* yb = y + (size_t)b * MM * DD;

    float acc[4][8];
    #pragma unroll
    for (int a = 0; a < 4; ++a)
        #pragma unroll
        for (int c = 0; c < 8; ++c) acc[a][c] = 0.0f;

    for (int dc = 0; dc < 4; ++dc) {         // K chunks of 32
        __syncthreads();
        // stage y chunk: 256 rows x 8 float4-slots, slot s stored at s^(j&7)
        #pragma unroll
        for (int it = 0; it < 8; ++it) {
            int k = t + it * 256;
            int j = k >> 3, s = k & 7;
            float4 v = *reinterpret_cast<const float4*>(yb + (size_t)j * DD + dc * 32 + s * 4);
            *reinterpret_cast<float4*>(&ysh[j * 32 + ((s ^ (j & 7)) << 2)]) = v;
        }
        // stage x chunk: 32 rows x 8 slots (reads are broadcast, no swizzle needed)
        {
            int j2 = t >> 3, s = t & 7;
            float4 v = *reinterpret_cast<const float4*>(xb + (size_t)j2 * DD + dc * 32 + s * 4);
            *reinterpret_cast<float4*>(&xsh[j2 * 32 + (s << 2)]) = v;
        }
        __syncthreads();
        #pragma unroll
        for (int s8 = 0; s8 < 8; ++s8) {
            float4 xf[4], yf[8];
            int sx = ((s8 ^ (tj & 7)) << 2);  // (tj+32*jj)&7 == tj&7
            #pragma unroll
            for (int ii = 0; ii < 4; ++ii)
                xf[ii] = *reinterpret_cast<const float4*>(&xsh[(ti * 4 + ii) * 32 + (s8 << 2)]);
            #pragma unroll
            for (int jj = 0; jj < 8; ++jj)
                yf[jj] = *reinterpret_cast<const float4*>(&ysh[(tj + 32 * jj) * 32 + sx]);
            #pragma unroll
            for (int ii = 0; ii < 4; ++ii)
                #pragma unroll
                for (int jj = 0; jj < 8; ++jj) {
                    acc[ii][jj] = fmaf(xf[ii].x, yf[jj].x, acc[ii][jj]);
                    acc[ii][jj] = fmaf(xf[ii].y, yf[jj].y, acc[ii][jj]);
                    acc[ii][jj] = fmaf(xf[ii].z, yf[jj].z, acc[ii][jj]);
                    acc[ii][jj] = fmaf(xf[ii].w, yf[jj].w, acc[ii][jj]);
                }
        }
    }
    #pragma unroll
    for (int ii = 0; ii < 4; ++ii) {
        size_t rowbase = ((size_t)b * NN + i0 + ti * 4 + ii) * MM;
        #pragma unroll
        for (int jj = 0; jj < 8; ++jj)
            dotm[rowbase + tj + 32 * jj] = acc[ii][jj];
    }
}

// ---------------- kernel 3: soft-DTW wavefront DP ----------------
// One wave per batch. Lane l owns columns j = 4l+1..4l+4 (R-matrix indexing).
// Lane l processes row r at step t = (r-1)+l. Left-neighbor values flow via shfl_up.
__global__ __launch_bounds__(64) void dp_kernel(const float* __restrict__ dotm,
                                                const float* __restrict__ norm_buf,
                                                float* __restrict__ bres) {
    int b = blockIdx.x;
    int l = threadIdx.x;
    const float* db = dotm + (size_t)b * NN * MM;
    const float* x2 = norm_buf + (size_t)b * NN;                      // ||x_i||^2
    const float* y2 = norm_buf + (size_t)BATCH * NN + (size_t)b * MM; // ||y_j||^2
    float4 y2v = *reinterpret_cast<const float4*>(y2 + 4 * l);

    float p0 = BIG, p1 = BIG, p2 = BIG, p3 = BIG;  // R[r-1, 4l+1..4l+4]
    float right = BIG, right_prev = BIG;            // my last-col values, steps t-1 / t-2
    float4 cbuf = make_float4(0.f, 0.f, 0.f, 0.f);
    float  x2buf = 0.f;
    if (l == 0) {  // preload for t=0 (lane 0, r=1 -> cost row 0)
        cbuf  = *reinterpret_cast<const float4*>(db);
        x2buf = x2[0];
    }

    for (int t = 0; t < NN + 63; ++t) {
        int  r      = t - l + 1;
        bool active = (r >= 1) && (r <= NN);
        float4 cd  = cbuf;
        float  x2r = x2buf;
        // prefetch next step's row (row index r) one iteration ahead
        if (r >= 0 && r < NN) {
            cbuf  = *reinterpret_cast<const float4*>(db + (size_t)r * MM + 4 * l);
            x2buf = x2[r];
        }
        float left_cur  = __shfl_up(right, 1);       // R[r,   4l]
        float left_diag = __shfl_up(right_prev, 1);  // R[r-1, 4l]
        if (l == 0) { left_cur = BIG; left_diag = (r == 1) ? 0.0f : BIG; }

        if (active) {
            // cost = x2 + y2 - 2*dot, folded here
            float c0 = fmaf(-2.0f, cd.x, x2r + y2v.x);
            float c1 = fmaf(-2.0f, cd.y, x2r + y2v.y);
            float c2 = fmaf(-2.0f, cd.z, x2r + y2v.z);
            float c3 = fmaf(-2.0f, cd.w, x2r + y2v.w);
            // off-chain partials: softmin2(up, diag)
            float h0 = softmin2(p0, left_diag);
            float h1 = softmin2(p1, p0);
            float h2 = softmin2(p2, p1);
            float h3 = softmin2(p3, p2);
            // serial left-dependency chain
            float v0 = c0 + softmin2(h0, left_cur);
            float v1 = c1 + softmin2(h1, v0);
            float v2 = c2 + softmin2(h2, v1);
            float v3 = c3 + softmin2(h3, v2);
            p0 = v0; p1 = v1; p2 = v2; p3 = v3;
            right_prev = right;
            right = v3;
        }
    }
    if (l == 63) bres[b] = right;  // R[256,256]
}

// ---------------- kernel 4: mean over batch ----------------
__global__ void reduce_kernel(const float* __restrict__ bres, float* __restrict__ out) {
    int l = threadIdx.x;
    float v = bres[l];
    #pragma unroll
    for (int o = 32; o; o >>= 1) v += __shfl_down(v, o);
    if (l == 0) out[0] = v * (1.0f / BATCH);
}

extern "C" void kernel_launch(void* const* d_in, const int* in_sizes, int n_in,
                              void* d_out, int out_size, void* d_ws, size_t ws_size,
                              hipStream_t stream) {
    const float* x = (const float*)d_in[0];
    const float* y = (const float*)d_in[1];
    float* out = (float*)d_out;
    float* ws  = (float*)d_ws;

    // ws layout (floats): dot matrix [64*256*256] | norms [32768] | batch results [64]
    // total = 16,908,544 bytes
    float* dotm     = ws;
    float* norm_buf = ws + (size_t)BATCH * NN * MM;
    float* bres     = norm_buf + 2 * BATCH * NN;

    norms_kernel <<<8192, 256, 0, stream>>>(x, y, norm_buf);
    cost_kernel  <<<dim3(BATCH, 8), 256, 0, stream>>>(x, y, dotm);
    dp_kernel    <<<BATCH, 64, 0, stream>>>(dotm, norm_buf, bres);
    reduce_kernel<<<1, 64, 0, stream>>>(bres, out);
}